// Round 2
// baseline (155.531 us; speedup 1.0000x reference)
//
#include <hip/hip_runtime.h>
#include <hip/hip_bf16.h>

typedef short bf16x8 __attribute__((ext_vector_type(8)));
typedef float f32x4 __attribute__((ext_vector_type(4)));

constexpr int Nn = 65536;
constexpr int Kk = 256;
constexpr int Dd = 512;
constexpr int BM = 64;
constexpr int BK = 64;

static __device__ __forceinline__ unsigned short f2bf(float f) {
  __hip_bfloat16 h = __float2bfloat16(f);
  return *reinterpret_cast<unsigned short*>(&h);
}

// Raw barrier: LDS-visibility wait only; global (vmcnt) prefetches stay in flight.
// asm "memory" clobbers fence compiler reordering of LDS ops across the barrier.
static __device__ __forceinline__ void rbar() {
  asm volatile("s_waitcnt lgkmcnt(0)" ::: "memory");
  __builtin_amdgcn_s_barrier();
  asm volatile("" ::: "memory");
}

// Convert clusters to bf16 (row-major [K][D]) and compute c2[k] = sum_d c[k][d]^2 in fp32.
__global__ __launch_bounds__(64)
void prep_clusters_kernel(const float* __restrict__ C,
                          unsigned short* __restrict__ CB,
                          float* __restrict__ c2) {
  const int k = blockIdx.x;
  const int t = threadIdx.x;
  const float* row = C + (size_t)k * Dd;
  float4 a = *reinterpret_cast<const float4*>(row + t * 8);
  float4 b = *reinterpret_cast<const float4*>(row + t * 8 + 4);
  float s = a.x * a.x + a.y * a.y + a.z * a.z + a.w * a.w
          + b.x * b.x + b.y * b.y + b.z * b.z + b.w * b.w;
  uint4 p;
  p.x = ((unsigned)f2bf(a.y) << 16) | f2bf(a.x);
  p.y = ((unsigned)f2bf(a.w) << 16) | f2bf(a.z);
  p.z = ((unsigned)f2bf(b.y) << 16) | f2bf(b.x);
  p.w = ((unsigned)f2bf(b.w) << 16) | f2bf(b.z);
  *reinterpret_cast<uint4*>(CB + (size_t)k * Dd + t * 8) = p;
  #pragma unroll
  for (int m = 1; m < 64; m <<= 1) s += __shfl_xor(s, m, 64);
  if (t == 0) c2[k] = s;
}

// Fused: xc GEMM (bf16 MFMA) + x2 (computed during A staging, fp32) + dist + q + row-normalize.
// Block: 256 threads (4 waves). Tile: BM=64 rows x all 256 clusters (wave w owns cols [64w,64w+64)).
__global__ __launch_bounds__(256, 4)
void cluster_q_kernel(const float* __restrict__ X,
                      const unsigned short* __restrict__ CB,
                      const float* __restrict__ c2g,
                      float* __restrict__ out) {
  __shared__ __align__(16) char Al[2][BM * BK * 2];  // swizzled bf16 A tiles, 8KB each
  __shared__ float x2s[BM];
  __shared__ __align__(16) float rowp[BM][4];        // per-wave row partial sums

  const int tid  = threadIdx.x;
  const int lane = tid & 63;
  const int wave = tid >> 6;
  const int hi   = lane >> 4;   // 0..3
  const int lo   = lane & 15;   // 0..15
  const int rbase = blockIdx.x * BM;
  const int arow  = tid >> 4;          // 0..15: staging row group
  const int acolb = (tid & 15) * 8;    // staging byte offset within LDS row (4 bf16)

  f32x4 acc[4][4];
  #pragma unroll
  for (int m = 0; m < 4; ++m)
    #pragma unroll
    for (int n = 0; n < 4; ++n)
      #pragma unroll
      for (int r = 0; r < 4; ++r) acc[m][n][r] = 0.f;

  float x2p[4] = {0.f, 0.f, 0.f, 0.f};
  float4 v[4];
  bf16x8 bA[4][2], bB[4][2];

  auto loadG = [&](int ks) {
    #pragma unroll
    for (int it = 0; it < 4; ++it)
      v[it] = *reinterpret_cast<const float4*>(
          &X[(size_t)(rbase + it * 16 + arow) * Dd + ks * BK + (tid & 15) * 4]);
  };

  auto stage = [&](int buf) {
    #pragma unroll
    for (int it = 0; it < 4; ++it) {
      const int row = it * 16 + arow;
      float4 f = v[it];
      x2p[it] += f.x * f.x + f.y * f.y + f.z * f.z + f.w * f.w;
      uint2 p;
      p.x = ((unsigned)f2bf(f.y) << 16) | f2bf(f.x);
      p.y = ((unsigned)f2bf(f.w) << 16) | f2bf(f.z);
      const int addr = (row * 128 + acolb) ^ ((row & 7) << 4);  // XOR-swizzle (G4)
      *reinterpret_cast<uint2*>(&Al[buf][addr]) = p;
    }
  };

  auto loadB = [&](int ks, bf16x8 (&bf)[4][2]) {
    #pragma unroll
    for (int n = 0; n < 4; ++n)
      #pragma unroll
      for (int ku = 0; ku < 2; ++ku)
        bf[n][ku] = *reinterpret_cast<const bf16x8*>(
            &CB[(size_t)(wave * 64 + n * 16 + lo) * Dd + ks * BK + ku * 32 + hi * 8]);
  };

  auto compute = [&](int buf, bf16x8 (&bf)[4][2]) {
    #pragma unroll
    for (int ku = 0; ku < 2; ++ku) {
      bf16x8 af[4];
      #pragma unroll
      for (int m = 0; m < 4; ++m) {
        const int row = m * 16 + lo;
        const int addr = (row * 128 + ku * 64 + hi * 16) ^ ((row & 7) << 4);
        af[m] = *reinterpret_cast<const bf16x8*>(&Al[buf][addr]);
      }
      #pragma unroll
      for (int m = 0; m < 4; ++m)
        #pragma unroll
        for (int n = 0; n < 4; ++n)
          acc[m][n] = __builtin_amdgcn_mfma_f32_16x16x32_bf16(af[m], bf[n][ku], acc[m][n], 0, 0, 0);
    }
  };

  // Pipeline prologue
  loadG(0);
  stage(0);
  loadG(1);
  loadB(0, bA);
  rbar();

  auto iter = [&](int ks, bf16x8 (&bcur)[4][2], bf16x8 (&bnxt)[4][2]) {
    if (ks < 7) stage((ks + 1) & 1);   // buf was last read at iter ks-1; barrier passed
    if (ks < 6) loadG(ks + 2);         // prefetch A-global one full iteration ahead
    if (ks < 7) loadB(ks + 1, bnxt);   // prefetch B frags (L2-resident)
    compute(ks & 1, bcur);
    rbar();                            // does NOT drain vmcnt: prefetches stay in flight
  };

  #pragma unroll
  for (int p = 0; p < 4; ++p) {
    iter(2 * p, bA, bB);
    iter(2 * p + 1, bB, bA);
  }

  // Finalize x2 (row sums of squares, fp32-exact): reduce across the 16 threads per row.
  #pragma unroll
  for (int it = 0; it < 4; ++it) {
    float s = x2p[it];
    s += __shfl_xor(s, 1); s += __shfl_xor(s, 2);
    s += __shfl_xor(s, 4); s += __shfl_xor(s, 8);
    if ((tid & 15) == 0) x2s[it * 16 + arow] = s;
  }
  __syncthreads();

  float c2v[4];
  #pragma unroll
  for (int n = 0; n < 4; ++n) c2v[n] = c2g[wave * 64 + n * 16 + lo];

  // dist -> q = 1/(1+dist) (ALPHA=1 => exponent 1), accumulate per-row partial sums.
  // v_rcp_f32 (~1 ulp): q ~ 1e-3, abs err ~1e-9 << 1e-4 threshold. Saves ~600 VALU ops/thread.
  float rs[4][4];
  #pragma unroll
  for (int m = 0; m < 4; ++m)
    #pragma unroll
    for (int r = 0; r < 4; ++r) rs[m][r] = 0.f;

  #pragma unroll
  for (int m = 0; m < 4; ++m) {
    #pragma unroll
    for (int n = 0; n < 4; ++n) {
      #pragma unroll
      for (int r = 0; r < 4; ++r) {
        const int row = m * 16 + hi * 4 + r;  // C/D: col=lane&15, row=(lane>>4)*4+reg
        float dist = x2s[row] + c2v[n] - 2.f * acc[m][n][r];
        dist = fmaxf(dist, 0.f);
        float qv = __builtin_amdgcn_rcpf(1.f + dist);
        acc[m][n][r] = qv;
        rs[m][r] += qv;
      }
    }
  }

  // Reduce row sums across the 16 cols held per lane-group, then across 4 waves via LDS.
  #pragma unroll
  for (int m = 0; m < 4; ++m)
    #pragma unroll
    for (int r = 0; r < 4; ++r) {
      float s = rs[m][r];
      s += __shfl_xor(s, 1); s += __shfl_xor(s, 2);
      s += __shfl_xor(s, 4); s += __shfl_xor(s, 8);
      rs[m][r] = s;
    }

  if (lo == 0) {
    #pragma unroll
    for (int m = 0; m < 4; ++m)
      #pragma unroll
      for (int r = 0; r < 4; ++r)
        rowp[m * 16 + hi * 4 + r][wave] = rs[m][r];
  }
  __syncthreads();

  float rinv[4][4];
  #pragma unroll
  for (int m = 0; m < 4; ++m)
    #pragma unroll
    for (int r = 0; r < 4; ++r) {
      float4 t = *reinterpret_cast<float4*>(rowp[m * 16 + hi * 4 + r]);
      rinv[m][r] = __builtin_amdgcn_rcpf(t.x + t.y + t.z + t.w);
    }

  #pragma unroll
  for (int m = 0; m < 4; ++m)
    #pragma unroll
    for (int n = 0; n < 4; ++n)
      #pragma unroll
      for (int r = 0; r < 4; ++r) {
        const int row = m * 16 + hi * 4 + r;
        out[(size_t)(rbase + row) * Kk + wave * 64 + n * 16 + lo] = acc[m][n][r] * rinv[m][r];
      }
}

extern "C" void kernel_launch(void* const* d_in, const int* in_sizes, int n_in,
                              void* d_out, int out_size, void* d_ws, size_t ws_size,
                              hipStream_t stream) {
  const float* X = reinterpret_cast<const float*>(d_in[0]);
  const float* C = reinterpret_cast<const float*>(d_in[1]);
  unsigned short* CB = reinterpret_cast<unsigned short*>(d_ws);           // 256 KB bf16 clusters
  float* c2 = reinterpret_cast<float*>(reinterpret_cast<char*>(d_ws) + (size_t)Kk * Dd * 2);
  prep_clusters_kernel<<<Kk, 64, 0, stream>>>(C, CB, c2);
  cluster_q_kernel<<<Nn / BM, 256, 0, stream>>>(X, CB, c2, reinterpret_cast<float*>(d_out));
}

// Round 3
// 61.758 us; speedup vs baseline: 2.5184x; 2.5184x over previous
//
#include <hip/hip_runtime.h>
#include <hip/hip_bf16.h>

typedef short bf16x8 __attribute__((ext_vector_type(8)));
typedef float f32x4 __attribute__((ext_vector_type(4)));

constexpr int Nn = 65536;
constexpr int Kk = 256;
constexpr int Dd = 512;
constexpr int BM = 64;
constexpr int BK = 64;

static __device__ __forceinline__ unsigned short f2bf(float f) {
  __hip_bfloat16 h = __float2bfloat16(f);
  return *reinterpret_cast<unsigned short*>(&h);
}

// Raw barrier: LDS-visibility wait only; global (vmcnt) prefetches stay in flight.
static __device__ __forceinline__ void rbar() {
  asm volatile("s_waitcnt lgkmcnt(0)" ::: "memory");
  __builtin_amdgcn_s_barrier();
  asm volatile("" ::: "memory");
}

// Convert clusters to bf16 (row-major [K][D]) and compute c2[k] = sum_d c[k][d]^2 in fp32.
__global__ __launch_bounds__(64)
void prep_clusters_kernel(const float* __restrict__ C,
                          unsigned short* __restrict__ CB,
                          float* __restrict__ c2) {
  const int k = blockIdx.x;
  const int t = threadIdx.x;
  const float* row = C + (size_t)k * Dd;
  float4 a = *reinterpret_cast<const float4*>(row + t * 8);
  float4 b = *reinterpret_cast<const float4*>(row + t * 8 + 4);
  float s = a.x * a.x + a.y * a.y + a.z * a.z + a.w * a.w
          + b.x * b.x + b.y * b.y + b.z * b.z + b.w * b.w;
  uint4 p;
  p.x = ((unsigned)f2bf(a.y) << 16) | f2bf(a.x);
  p.y = ((unsigned)f2bf(a.w) << 16) | f2bf(a.z);
  p.z = ((unsigned)f2bf(b.y) << 16) | f2bf(b.x);
  p.w = ((unsigned)f2bf(b.w) << 16) | f2bf(b.z);
  *reinterpret_cast<uint4*>(CB + (size_t)k * Dd + t * 8) = p;
  #pragma unroll
  for (int m = 1; m < 64; m <<= 1) s += __shfl_xor(s, m, 64);
  if (t == 0) c2[k] = s;
}

// Fused: xc GEMM (bf16 MFMA) + x2 (computed during A staging, fp32) + dist + q + row-normalize.
// Block: 256 threads (4 waves). Tile: BM=64 rows x all 256 clusters (wave w owns cols [64w,64w+64)).
// launch_bounds(256,2): (256,4) caps VGPR at 64 -> catastrophic spill (R2: +330MB scratch traffic).
__global__ __launch_bounds__(256, 2)
void cluster_q_kernel(const float* __restrict__ X,
                      const unsigned short* __restrict__ CB,
                      const float* __restrict__ c2g,
                      float* __restrict__ out) {
  __shared__ __align__(16) char Al[2][BM * BK * 2];  // swizzled bf16 A tiles, 8KB each
  __shared__ float x2s[BM];
  __shared__ __align__(16) float rowp[BM][4];        // per-wave row partial sums

  const int tid  = threadIdx.x;
  const int lane = tid & 63;
  const int wave = tid >> 6;
  const int hi   = lane >> 4;   // 0..3
  const int lo   = lane & 15;   // 0..15
  const int rbase = blockIdx.x * BM;
  const int arow  = tid >> 4;          // 0..15: staging row group
  const int acolb = (tid & 15) * 8;    // staging byte offset within LDS row (4 bf16)

  f32x4 acc[4][4];
  #pragma unroll
  for (int m = 0; m < 4; ++m)
    #pragma unroll
    for (int n = 0; n < 4; ++n)
      #pragma unroll
      for (int r = 0; r < 4; ++r) acc[m][n][r] = 0.f;

  float x2p[4] = {0.f, 0.f, 0.f, 0.f};
  float4 v[4];
  bf16x8 bA[4][2], bB[4][2];

  auto loadG = [&](int ks) {
    #pragma unroll
    for (int it = 0; it < 4; ++it)
      v[it] = *reinterpret_cast<const float4*>(
          &X[(size_t)(rbase + it * 16 + arow) * Dd + ks * BK + (tid & 15) * 4]);
  };

  auto stage = [&](int buf) {
    #pragma unroll
    for (int it = 0; it < 4; ++it) {
      const int row = it * 16 + arow;
      float4 f = v[it];
      x2p[it] += f.x * f.x + f.y * f.y + f.z * f.z + f.w * f.w;
      uint2 p;
      p.x = ((unsigned)f2bf(f.y) << 16) | f2bf(f.x);
      p.y = ((unsigned)f2bf(f.w) << 16) | f2bf(f.z);
      const int addr = (row * 128 + acolb) ^ ((row & 7) << 4);  // XOR-swizzle (G4)
      *reinterpret_cast<uint2*>(&Al[buf][addr]) = p;
    }
  };

  auto loadB = [&](int ks, bf16x8 (&bf)[4][2]) {
    #pragma unroll
    for (int n = 0; n < 4; ++n)
      #pragma unroll
      for (int ku = 0; ku < 2; ++ku)
        bf[n][ku] = *reinterpret_cast<const bf16x8*>(
            &CB[(size_t)(wave * 64 + n * 16 + lo) * Dd + ks * BK + ku * 32 + hi * 8]);
  };

  auto compute = [&](int buf, bf16x8 (&bf)[4][2]) {
    #pragma unroll
    for (int ku = 0; ku < 2; ++ku) {
      bf16x8 af[4];
      #pragma unroll
      for (int m = 0; m < 4; ++m) {
        const int row = m * 16 + lo;
        const int addr = (row * 128 + ku * 64 + hi * 16) ^ ((row & 7) << 4);
        af[m] = *reinterpret_cast<const bf16x8*>(&Al[buf][addr]);
      }
      #pragma unroll
      for (int m = 0; m < 4; ++m)
        #pragma unroll
        for (int n = 0; n < 4; ++n)
          acc[m][n] = __builtin_amdgcn_mfma_f32_16x16x32_bf16(af[m], bf[n][ku], acc[m][n], 0, 0, 0);
    }
  };

  // Pipeline prologue
  loadG(0);
  stage(0);
  loadG(1);
  loadB(0, bA);
  rbar();

  auto iter = [&](int ks, bf16x8 (&bcur)[4][2], bf16x8 (&bnxt)[4][2]) {
    if (ks < 7) stage((ks + 1) & 1);   // buf was last read at iter ks-1; barrier passed
    if (ks < 6) loadG(ks + 2);         // prefetch A-global one full iteration ahead
    if (ks < 7) loadB(ks + 1, bnxt);   // prefetch B frags (L2-resident)
    compute(ks & 1, bcur);
    rbar();                            // does NOT drain vmcnt: prefetches stay in flight
  };

  #pragma unroll
  for (int p = 0; p < 4; ++p) {
    iter(2 * p, bA, bB);
    iter(2 * p + 1, bB, bA);
  }

  // Finalize x2 (row sums of squares, fp32-exact): reduce across the 16 threads per row.
  #pragma unroll
  for (int it = 0; it < 4; ++it) {
    float s = x2p[it];
    s += __shfl_xor(s, 1); s += __shfl_xor(s, 2);
    s += __shfl_xor(s, 4); s += __shfl_xor(s, 8);
    if ((tid & 15) == 0) x2s[it * 16 + arow] = s;
  }
  __syncthreads();

  float c2v[4];
  #pragma unroll
  for (int n = 0; n < 4; ++n) c2v[n] = c2g[wave * 64 + n * 16 + lo];

  // dist -> q = 1/(1+dist) (ALPHA=1 => exponent 1), accumulate per-row partial sums.
  // v_rcp_f32 (~1 ulp): q ~ 1e-3, abs err ~1e-9 << 1e-4 threshold.
  float rs[4][4];
  #pragma unroll
  for (int m = 0; m < 4; ++m)
    #pragma unroll
    for (int r = 0; r < 4; ++r) rs[m][r] = 0.f;

  #pragma unroll
  for (int m = 0; m < 4; ++m) {
    #pragma unroll
    for (int n = 0; n < 4; ++n) {
      #pragma unroll
      for (int r = 0; r < 4; ++r) {
        const int row = m * 16 + hi * 4 + r;  // C/D: col=lane&15, row=(lane>>4)*4+reg
        float dist = x2s[row] + c2v[n] - 2.f * acc[m][n][r];
        dist = fmaxf(dist, 0.f);
        float qv = __builtin_amdgcn_rcpf(1.f + dist);
        acc[m][n][r] = qv;
        rs[m][r] += qv;
      }
    }
  }

  // Reduce row sums across the 16 cols held per lane-group, then across 4 waves via LDS.
  #pragma unroll
  for (int m = 0; m < 4; ++m)
    #pragma unroll
    for (int r = 0; r < 4; ++r) {
      float s = rs[m][r];
      s += __shfl_xor(s, 1); s += __shfl_xor(s, 2);
      s += __shfl_xor(s, 4); s += __shfl_xor(s, 8);
      rs[m][r] = s;
    }

  if (lo == 0) {
    #pragma unroll
    for (int m = 0; m < 4; ++m)
      #pragma unroll
      for (int r = 0; r < 4; ++r)
        rowp[m * 16 + hi * 4 + r][wave] = rs[m][r];
  }
  __syncthreads();

  float rinv[4][4];
  #pragma unroll
  for (int m = 0; m < 4; ++m)
    #pragma unroll
    for (int r = 0; r < 4; ++r) {
      float4 t = *reinterpret_cast<float4*>(rowp[m * 16 + hi * 4 + r]);
      rinv[m][r] = __builtin_amdgcn_rcpf(t.x + t.y + t.z + t.w);
    }

  #pragma unroll
  for (int m = 0; m < 4; ++m)
    #pragma unroll
    for (int n = 0; n < 4; ++n)
      #pragma unroll
      for (int r = 0; r < 4; ++r) {
        const int row = m * 16 + hi * 4 + r;
        out[(size_t)(rbase + row) * Kk + wave * 64 + n * 16 + lo] = acc[m][n][r] * rinv[m][r];
      }
}

extern "C" void kernel_launch(void* const* d_in, const int* in_sizes, int n_in,
                              void* d_out, int out_size, void* d_ws, size_t ws_size,
                              hipStream_t stream) {
  const float* X = reinterpret_cast<const float*>(d_in[0]);
  const float* C = reinterpret_cast<const float*>(d_in[1]);
  unsigned short* CB = reinterpret_cast<unsigned short*>(d_ws);           // 256 KB bf16 clusters
  float* c2 = reinterpret_cast<float*>(reinterpret_cast<char*>(d_ws) + (size_t)Kk * Dd * 2);
  prep_clusters_kernel<<<Kk, 64, 0, stream>>>(C, CB, c2);
  cluster_q_kernel<<<Nn / BM, 256, 0, stream>>>(X, CB, c2, reinterpret_cast<float*>(d_out));
}